// Round 2
// baseline (96.852 us; speedup 1.0000x reference)
//
#include <hip/hip_runtime.h>

#define BB   128        // batch
#define TT   4096       // time
#define NSH  257        // shifts -128..+128 -> j = 0..256
#define PAD  128
#define LTOT 4352.0f    // padded length
#define NCH  4          // t-chunks per row
#define TC   1024       // t per chunk
#define PPW  (TC + 256) // pp window floats per chunk

__device__ __forceinline__ float wave_sum(float v) {
    #pragma unroll
    for (int m = 32; m; m >>= 1) v += __shfl_xor(v, m, 64);
    return v;
}

// Partial cross-correlations cov[b][chunk][j] + per-chunk stats. No global atomics,
// no zero-init needed: every block plain-stores its own slots.
extern "C" __global__ __launch_bounds__(1024)
void k_corr(const float* __restrict__ preds, const float* __restrict__ labels,
            float* __restrict__ cov_ws, float* __restrict__ stats_ws) {
    __shared__ float pp_s[PPW];    // P[t0 + v], P[x] = preds[x-128] zero-padded
    __shared__ float lab_s[TC];
    __shared__ float cov_s[NSH];
    __shared__ float st_s[4];

    const int bid = blockIdx.x;
    const int b   = bid >> 2;       // row
    const int c   = bid & 3;        // chunk
    const int t0  = c * TC;
    const int tid = threadIdx.x;

    const float* pr = preds  + b * TT;
    const float* lr = labels + b * TT;

    // ---- stage (coalesced) ----
    #pragma unroll
    for (int v = tid; v < PPW; v += 1024) {
        int idx = t0 + v - PAD;
        pp_s[v] = (idx >= 0 && idx < TT) ? pr[idx] : 0.0f;
    }
    lab_s[tid] = lr[t0 + tid];              // TC == blockDim
    if (tid < NSH) cov_s[tid] = 0.0f;
    if (tid < 4)   st_s[tid]  = 0.0f;
    __syncthreads();

    // ---- main: lane = 4 consecutive shifts (j = 4l..4l+3), wave = 64-t subchunk ----
    const int l    = tid & 63;
    const int wv   = tid >> 6;              // 16 waves
    const int tq0  = wv * (TC / 16);        // 64 t per wave
    const int boff = 256 - 4 * l;

    float4 prev = *reinterpret_cast<const float4*>(&pp_s[tq0 + boff - 4]);
    float a0 = 0.f, a1 = 0.f, a2 = 0.f, a3 = 0.f;

    #pragma unroll
    for (int tq = tq0; tq < tq0 + TC / 16; tq += 4) {   // 16 iters
        const float4 lab = *reinterpret_cast<const float4*>(&lab_s[tq]);        // broadcast
        const float4 cur = *reinterpret_cast<const float4*>(&pp_s[tq + boff]);  // conflict-free b128
        a0 += lab.x * cur.x;  a0 += lab.y * cur.y;  a0 += lab.z * cur.z;  a0 += lab.w * cur.w;
        a1 += lab.x * prev.w; a1 += lab.y * cur.x;  a1 += lab.z * cur.y;  a1 += lab.w * cur.z;
        a2 += lab.x * prev.z; a2 += lab.y * prev.w; a2 += lab.z * cur.x;  a2 += lab.w * cur.y;
        a3 += lab.x * prev.y; a3 += lab.y * prev.z; a3 += lab.z * prev.w; a3 += lab.w * cur.x;
        prev = cur;
    }
    atomicAdd(&cov_s[4 * l + 0], a0);
    atomicAdd(&cov_s[4 * l + 1], a1);
    atomicAdd(&cov_s[4 * l + 2], a2);
    atomicAdd(&cov_s[4 * l + 3], a3);

    // ---- shift j=256: sum labels[t]*P[t] (one elem per thread) ----
    {
        float e = wave_sum(lab_s[tid] * pp_s[tid]);
        if (l == 0) atomicAdd(&cov_s[256], e);
    }

    // ---- per-chunk stats (one elem per thread) ----
    {
        float pv = pp_s[tid + PAD];          // = preds[t0+tid]
        float lv = lab_s[tid];
        float sp  = wave_sum(pv);
        float spp = wave_sum(pv * pv);
        float sl  = wave_sum(lv);
        float sll = wave_sum(lv * lv);
        if (l == 0) {
            atomicAdd(&st_s[0], sp);
            atomicAdd(&st_s[1], spp);
            atomicAdd(&st_s[2], sl);
            atomicAdd(&st_s[3], sll);
        }
    }

    __syncthreads();
    if (tid < NSH) cov_ws[bid * NSH + tid] = cov_s[tid];
    if (tid < 4)   stats_ws[bid * 4 + tid] = st_s[tid];
}

// fold chunk partials -> corr -> max over shifts -> mean over batch
extern "C" __global__ __launch_bounds__(1024)
void k_final(const float* __restrict__ cov_ws, const float* __restrict__ stats_ws,
             float* __restrict__ out) {
    __shared__ float part[16];
    const int tid  = threadIdx.x;
    const int lane = tid & 63;
    const int wv   = tid >> 6;   // 16 waves

    float sum = 0.f;
    for (int b = wv; b < BB; b += 16) {
        float Sp = 0.f, Spp = 0.f, Sl = 0.f, Sll = 0.f;
        #pragma unroll
        for (int c = 0; c < NCH; ++c) {
            const float* st = stats_ws + (b * NCH + c) * 4;
            Sp += st[0]; Spp += st[1]; Sl += st[2]; Sll += st[3];
        }
        float xn2 = Spp - Sp * Sp / LTOT;
        float yn2 = Sll - Sl * Sl / LTOT;
        float inv = rsqrtf(xn2 * yn2);
        float cst = Sp * Sl / LTOT;
        float mx = -1e30f;
        for (int j = lane; j < NSH; j += 64) {
            float cv = 0.f;
            #pragma unroll
            for (int c = 0; c < NCH; ++c) cv += cov_ws[(b * NCH + c) * NSH + j];
            mx = fmaxf(mx, (cv - cst) * inv);
        }
        #pragma unroll
        for (int m = 32; m; m >>= 1) mx = fmaxf(mx, __shfl_xor(mx, m, 64));
        sum += 1.0f - mx;
    }
    if (lane == 0) part[wv] = sum;
    __syncthreads();
    if (tid == 0) {
        float t = 0.f;
        #pragma unroll
        for (int w = 0; w < 16; ++w) t += part[w];
        out[0] = t * (1.0f / BB);
    }
}

extern "C" void kernel_launch(void* const* d_in, const int* in_sizes, int n_in,
                              void* d_out, int out_size, void* d_ws, size_t ws_size,
                              hipStream_t stream) {
    const float* preds  = (const float*)d_in[0];
    const float* labels = (const float*)d_in[1];
    float* out      = (float*)d_out;
    float* cov_ws   = (float*)d_ws;                    // [BB*NCH][NSH]
    float* stats_ws = cov_ws + BB * NCH * NSH;         // [BB*NCH][4]

    hipLaunchKernelGGL(k_corr, dim3(BB * NCH), dim3(1024), 0, stream,
                       preds, labels, cov_ws, stats_ws);
    hipLaunchKernelGGL(k_final, dim3(1), dim3(1024), 0, stream,
                       cov_ws, stats_ws, out);
}